// Round 10
// baseline (786.671 us; speedup 1.0000x reference)
//
#include <hip/hip_runtime.h>
#include <hip/hip_cooperative_groups.h>
#include <math.h>

namespace cg = cooperative_groups;

#define NR 8192
#define INF_ 512
#define OUTF 256
#define ALPHA 0.2f

typedef __attribute__((ext_vector_type(8))) short bf16x8;   // 8 bf16 = 4 VGPR
typedef __attribute__((ext_vector_type(4))) float f32x4;    // MFMA accumulator

#define MFMA(a, b, c) __builtin_amdgcn_mfma_f32_16x16x32_bf16((a), (b), (c), 0, 0, 0)

__device__ __forceinline__ ushort f2bf(float x) {  // RNE fp32->bf16
    unsigned u = __float_as_uint(x);
    return (ushort)((u + 0x7fff + ((u >> 16) & 1)) >> 16);
}
__device__ __forceinline__ float bf2f(ushort b) { return __uint_as_float((unsigned)b << 16); }

// ---------------- Kernel 1: H = X @ W (split-bf16 MFMA, inline conversion) ----
// 64x64 tile, 4 waves, BK=32. fp32 X/W loaded coalesced, converted to bf16
// hi/lo at LDS-staging time (kills the separate conversion kernels+traffic).
// LDS [kg4][idx64][8bf16], kg stride 512 ushorts; frag reads quarter-wave-
// contiguous 256B ds_read_b128 (conflict-free).
__global__ __launch_bounds__(256) void k_gemm(const float* __restrict__ X,
                                              const float* __restrict__ W,
                                              float* __restrict__ H) {
    __shared__ ushort sAhi[2048], sAlo[2048], sBhi[2048], sBlo[2048];
    const int tid = threadIdx.x;
    const int brow = blockIdx.x * 64, bcol = blockIdx.y * 64;
    const int lane = tid & 63, wr = tid >> 6;
    const int s_kg = tid >> 6, s_i = tid & 63;
    const float* gA = X + (size_t)(brow + s_i) * INF_ + s_kg * 8;
    const float* gB = W + (size_t)(s_kg * 8) * OUTF + bcol + s_i;
    const int sw = tid * 8;
    const int fr = lane & 15, kg = lane >> 4;
    const int aoff = kg * 512 + (wr * 16 + fr) * 8;
    const int boff = kg * 512 + fr * 8;

    f32x4 acc0 = {0.f,0.f,0.f,0.f}, acc1 = {0.f,0.f,0.f,0.f};
    f32x4 acc2 = {0.f,0.f,0.f,0.f}, acc3 = {0.f,0.f,0.f,0.f};

    float ra[8], rb[8];
    {
        float4 v0 = *(const float4*)gA, v1 = *(const float4*)(gA + 4);
        ra[0]=v0.x; ra[1]=v0.y; ra[2]=v0.z; ra[3]=v0.w;
        ra[4]=v1.x; ra[5]=v1.y; ra[6]=v1.z; ra[7]=v1.w;
#pragma unroll
        for (int j = 0; j < 8; ++j) rb[j] = gB[j * OUTF];
    }
    for (int t = 0; t < INF_ / 32; ++t) {
        ushort ah[8], al[8], bh[8], bl[8];
#pragma unroll
        for (int j = 0; j < 8; ++j) {
            ah[j] = f2bf(ra[j]); al[j] = f2bf(ra[j] - bf2f(ah[j]));
            bh[j] = f2bf(rb[j]); bl[j] = f2bf(rb[j] - bf2f(bh[j]));
        }
        *(uint4*)&sAhi[sw] = *(uint4*)ah; *(uint4*)&sAlo[sw] = *(uint4*)al;
        *(uint4*)&sBhi[sw] = *(uint4*)bh; *(uint4*)&sBlo[sw] = *(uint4*)bl;
        __syncthreads();
        if (t < INF_ / 32 - 1) {
            const float* pA = gA + (t + 1) * 32;
            const float* pB = gB + (size_t)(t + 1) * 32 * OUTF;
            float4 v0 = *(const float4*)pA, v1 = *(const float4*)(pA + 4);
            ra[0]=v0.x; ra[1]=v0.y; ra[2]=v0.z; ra[3]=v0.w;
            ra[4]=v1.x; ra[5]=v1.y; ra[6]=v1.z; ra[7]=v1.w;
#pragma unroll
            for (int j = 0; j < 8; ++j) rb[j] = pB[j * OUTF];
        }
        bf16x8 ahi = *(const bf16x8*)&sAhi[aoff];
        bf16x8 alo = *(const bf16x8*)&sAlo[aoff];
        bf16x8 bh0 = *(const bf16x8*)&sBhi[boff];
        bf16x8 bl0 = *(const bf16x8*)&sBlo[boff];
        bf16x8 bh1 = *(const bf16x8*)&sBhi[boff + 128];
        bf16x8 bl1 = *(const bf16x8*)&sBlo[boff + 128];
        bf16x8 bh2 = *(const bf16x8*)&sBhi[boff + 256];
        bf16x8 bl2 = *(const bf16x8*)&sBlo[boff + 256];
        bf16x8 bh3 = *(const bf16x8*)&sBhi[boff + 384];
        bf16x8 bl3 = *(const bf16x8*)&sBlo[boff + 384];
        acc0 = MFMA(ahi, bh0, acc0); acc0 = MFMA(ahi, bl0, acc0); acc0 = MFMA(alo, bh0, acc0);
        acc1 = MFMA(ahi, bh1, acc1); acc1 = MFMA(ahi, bl1, acc1); acc1 = MFMA(alo, bh1, acc1);
        acc2 = MFMA(ahi, bh2, acc2); acc2 = MFMA(ahi, bl2, acc2); acc2 = MFMA(alo, bh2, acc2);
        acc3 = MFMA(ahi, bh3, acc3); acc3 = MFMA(ahi, bl3, acc3); acc3 = MFMA(alo, bh3, acc3);
        __syncthreads();
    }
    const int orow = brow + wr * 16 + kg * 4;   // C/D: col=lane&15, row=(lane>>4)*4+q
    const int ocol = bcol + fr;
#pragma unroll
    for (int q = 0; q < 4; ++q) {
        H[(size_t)(orow + q) * OUTF + ocol + 0]  = acc0[q];
        H[(size_t)(orow + q) * OUTF + ocol + 16] = acc1[q];
        H[(size_t)(orow + q) * OUTF + ocol + 32] = acc2[q];
        H[(size_t)(orow + q) * OUTF + ocol + 48] = acc3[q];
    }
}

// ---------------- Kernel 2: fused cooperative pipeline ----------------
struct KParams {
    const float* H; const float* a;
    float* dstv; float* dsts; int* perm;
    float* Splus; float* Sminus;
    float* csP; float* csM; float* ebP; float* ebM;
    float* chunkP; float* chunkM; float* offP; float* offM;
    float* PrefP; float* PrefM; float* out;
};

__global__ __launch_bounds__(256) void k_fused(KParams p) {
    cg::grid_group grid = cg::this_grid();
    __shared__ float key[NR];                    // 32 KB (P2)
    __shared__ float lpP[32], lpM[32];           // local inclusive weight prefixes
    __shared__ float swp[32], swm[32];           // chunk weights (persist P3a->P6)
    __shared__ int   sp[32];                     // chunk perm
    __shared__ float ws0[4], ws1[4];             // cross-wave scan scratch
    __shared__ float ssrc[32];                   // src values for this block's rows
    __shared__ int   stt[32];
    __shared__ float scP[32], scM[32], sinv[32];

    const int b = blockIdx.x, tid = threadIdx.x;
    const int lane = tid & 63, wv = tid >> 6;

    // ---- P1: src/dst dot products (block b owns rows b*32..b*32+31) ----
    {
        float4 a1 = *(const float4*)(p.a + lane * 4);
        float4 a2 = *(const float4*)(p.a + OUTF + lane * 4);
#pragma unroll
        for (int j = 0; j < 8; ++j) {
            int row = b * 32 + wv * 8 + j;
            float4 hv = *(const float4*)(p.H + (size_t)row * OUTF + lane * 4);
            float s = hv.x*a1.x + hv.y*a1.y + hv.z*a1.z + hv.w*a1.w;
            float d = hv.x*a2.x + hv.y*a2.y + hv.z*a2.z + hv.w*a2.w;
#pragma unroll
            for (int o = 32; o > 0; o >>= 1) { s += __shfl_down(s, o); d += __shfl_down(d, o); }
            if (lane == 0) { ssrc[wv * 8 + j] = s; p.dstv[row] = d; }
        }
    }
    __threadfence(); grid.sync();

    // ---- P2: rank-by-counting (bank-staggered LDS scan) ----
    {
#pragma unroll
        for (int i = 0; i < 8; ++i)
            *(float4*)(key + 4 * (tid + 256 * i)) = *(const float4*)(p.dstv + 4 * (tid + 256 * i));
        __syncthreads();
        const int el = b * 32 + (tid >> 3);
        const int sub = tid & 7;
        const float my = key[el];
        const int sbase = sub << 10;
        int cnt = 0;
#pragma unroll 4
        for (int i = 0; i < 256; ++i) {
            const int off = ((i + sub) << 2) & 1023;
            const int k0 = sbase + off;
            float4 v = *(const float4*)(key + k0);
            cnt += (int)((v.x < my) | ((v.x == my) & (k0 + 0 < el)));
            cnt += (int)((v.y < my) | ((v.y == my) & (k0 + 1 < el)));
            cnt += (int)((v.z < my) | ((v.z == my) & (k0 + 2 < el)));
            cnt += (int)((v.w < my) | ((v.w == my) & (k0 + 3 < el)));
        }
        cnt += __shfl_down(cnt, 4);
        cnt += __shfl_down(cnt, 2);
        cnt += __shfl_down(cnt, 1);
        if (sub == 0) { p.dsts[cnt] = my; p.perm[cnt] = el; }
    }
    __threadfence(); grid.sync();

    const float D = p.dsts[NR - 1];

    // ---- P3a: chunk weights, local scan, chunk scalar sums ----
    if (tid < 32) {
        int g = b * 32 + tid;
        float kv = p.dsts[g];
        float wp = expf(kv - D), wm = expf(ALPHA * kv);
        swp[tid] = wp; swm[tid] = wm;
        sp[tid] = p.perm[g];
        float ip = wp, im = wm;
#pragma unroll
        for (int o = 1; o < 32; o <<= 1) {
            float tp = __shfl_up(ip, o), tm = __shfl_up(im, o);
            if (tid >= o) { ip += tp; im += tm; }
        }
        lpP[tid] = ip; lpM[tid] = im;
        if (tid == 31) { p.csP[b] = ip; p.csM[b] = im; }
    }
    __threadfence(); grid.sync();

    // ---- P3b: block 0 scans the 256 chunk scalar sums ----
    if (b == 0) {
        float vP = p.csP[tid], vM = p.csM[tid];
        float iP = vP, iM = vM;
#pragma unroll
        for (int o = 1; o < 64; o <<= 1) {
            float tP = __shfl_up(iP, o), tM = __shfl_up(iM, o);
            if (lane >= o) { iP += tP; iM += tM; }
        }
        if (lane == 63) { ws0[wv] = iP; ws1[wv] = iM; }
        __syncthreads();
        float bP = 0.f, bM = 0.f;
#pragma unroll
        for (int w = 0; w < 4; ++w) if (w < wv) { bP += ws0[w]; bM += ws1[w]; }
        p.ebP[tid] = bP + iP - vP;
        p.ebM[tid] = bM + iM - vM;
    }
    __threadfence(); grid.sync();

    // ---- P3c: scalar prefix arrays ----
    if (tid < 32) {
        int g = b * 32 + tid;
        float bP = p.ebP[b], bM = p.ebM[b];
        p.Splus[g + 1]  = bP + lpP[tid];
        p.Sminus[g + 1] = bM + lpM[tid];
    }
    if (b == 0 && tid == 0) { p.Splus[0] = 0.f; p.Sminus[0] = 0.f; }

    // ---- P4: chunk vector sums (8 gathered H rows in flight) ----
    {
        const int f = tid;
        float aP = 0.f, aM = 0.f;
        for (int k0 = 0; k0 < 32; k0 += 8) {
            float hv[8];
#pragma unroll
            for (int j = 0; j < 8; ++j) hv[j] = p.H[(size_t)sp[k0 + j] * OUTF + f];
#pragma unroll
            for (int j = 0; j < 8; ++j) {
                aP = fmaf(swp[k0 + j], hv[j], aP);
                aM = fmaf(swm[k0 + j], hv[j], aM);
            }
        }
        p.chunkP[(size_t)b * OUTF + f] = aP;
        p.chunkM[(size_t)b * OUTF + f] = aM;
    }
    __threadfence(); grid.sync();

    // ---- P5: per-column scan of chunk sums (block b = column b) ----
    {
        const int fc = b;
        float vP = p.chunkP[(size_t)tid * OUTF + fc];
        float vM = p.chunkM[(size_t)tid * OUTF + fc];
        float iP = vP, iM = vM;
#pragma unroll
        for (int o = 1; o < 64; o <<= 1) {
            float tP = __shfl_up(iP, o), tM = __shfl_up(iM, o);
            if (lane >= o) { iP += tP; iM += tM; }
        }
        if (lane == 63) { ws0[wv] = iP; ws1[wv] = iM; }
        __syncthreads();
        float bP = 0.f, bM = 0.f;
#pragma unroll
        for (int w = 0; w < 4; ++w) if (w < wv) { bP += ws0[w]; bM += ws1[w]; }
        iP += bP; iM += bM;
        p.offP[(size_t)tid * OUTF + fc] = iP - vP;
        p.offM[(size_t)tid * OUTF + fc] = iM - vM;
        if (tid == 255) {
            p.PrefP[(size_t)NR * OUTF + fc] = iP;   // grand totals
            p.PrefM[(size_t)NR * OUTF + fc] = iM;
        }
    }
    __threadfence(); grid.sync();

    // ---- P6: write Pref rows for chunk b ----
    {
        const int f = tid;
        float aP = p.offP[(size_t)b * OUTF + f];
        float aM = p.offM[(size_t)b * OUTF + f];
        for (int k0 = 0; k0 < 32; k0 += 8) {
            float hv[8];
#pragma unroll
            for (int j = 0; j < 8; ++j) hv[j] = p.H[(size_t)sp[k0 + j] * OUTF + f];
#pragma unroll
            for (int j = 0; j < 8; ++j) {
                int g = b * 32 + k0 + j;
                p.PrefP[(size_t)g * OUTF + f] = aP;
                p.PrefM[(size_t)g * OUTF + f] = aM;
                aP = fmaf(swp[k0 + j], hv[j], aP);
                aM = fmaf(swm[k0 + j], hv[j], aM);
            }
        }
    }
    __threadfence(); grid.sync();

    // ---- P7: per-row combine + ELU (rows b*32..b*32+31) ----
    {
        const float SPtot = p.Splus[NR];
        if (tid < 32) {
            float si = ssrc[tid];
            float thr = -si;
            int lo = 0, hi = NR;
            while (lo < hi) {
                int mid = (lo + hi) >> 1;
                if (p.dsts[mid] <= thr) lo = mid + 1; else hi = mid;
            }
            float cP = expf(si + D), cM = expf(ALPHA * si);
            float SP = SPtot - p.Splus[lo], SM = p.Sminus[lo];
            stt[tid] = lo; scP[tid] = cP; scM[tid] = cM;
            sinv[tid] = 1.f / (cP * SP + cM * SM);
        }
        __syncthreads();
        const float totP = p.PrefP[(size_t)NR * OUTF + tid];
        for (int r = 0; r < 32; ++r) {
            int t_ = stt[r];
            float pPv = totP - p.PrefP[(size_t)t_ * OUTF + tid];
            float pMv = p.PrefM[(size_t)t_ * OUTF + tid];
            float v = (scP[r] * pPv + scM[r] * pMv) * sinv[r];
            p.out[(size_t)(b * 32 + r) * OUTF + tid] = v > 0.f ? v : expm1f(v);
        }
    }
}

extern "C" void kernel_launch(void* const* d_in, const int* in_sizes, int n_in,
                              void* d_out, int out_size, void* d_ws, size_t ws_size,
                              hipStream_t stream) {
    const float* X = (const float*)d_in[0];
    // d_in[1] = adj (unused by reference forward)
    const float* W = (const float*)d_in[2];
    const float* a = (const float*)d_in[3];
    float* out = (float*)d_out;

    char* ws = (char*)d_ws;
    size_t off = 0;
    auto carve = [&](size_t bytes) -> void* {
        void* ptr = ws + off;
        off += (bytes + 1023) & ~(size_t)1023;
        return ptr;
    };
    float* H      = (float*)carve((size_t)NR * OUTF * 4);
    float* dstv   = (float*)carve(NR * 4);
    float* dsts   = (float*)carve(NR * 4);
    int*   perm   = (int*)carve(NR * 4);
    float* Splus  = (float*)carve((NR + 1) * 4);
    float* Sminus = (float*)carve((NR + 1) * 4);
    float* csP    = (float*)carve(256 * 4);
    float* csM    = (float*)carve(256 * 4);
    float* ebP    = (float*)carve(256 * 4);
    float* ebM    = (float*)carve(256 * 4);
    float* chunkP = (float*)carve(256 * OUTF * 4);
    float* chunkM = (float*)carve(256 * OUTF * 4);
    float* offP   = (float*)carve(256 * OUTF * 4);
    float* offM   = (float*)carve(256 * OUTF * 4);
    float* PrefP  = (float*)carve((size_t)(NR + 1) * OUTF * 4);
    float* PrefM  = (float*)carve((size_t)(NR + 1) * OUTF * 4);

    k_gemm<<<dim3(NR / 64, OUTF / 64), 256, 0, stream>>>(X, W, H);

    KParams p;
    p.H = H; p.a = a; p.dstv = dstv; p.dsts = dsts; p.perm = perm;
    p.Splus = Splus; p.Sminus = Sminus;
    p.csP = csP; p.csM = csM; p.ebP = ebP; p.ebM = ebM;
    p.chunkP = chunkP; p.chunkM = chunkM; p.offP = offP; p.offM = offM;
    p.PrefP = PrefP; p.PrefM = PrefM; p.out = out;
    void* args[] = {&p};
    hipLaunchCooperativeKernel((const void*)k_fused, dim3(256), dim3(256),
                               args, 0, stream);
}

// Round 13
// 421.685 us; speedup vs baseline: 1.8655x; 1.8655x over previous
//
#include <hip/hip_runtime.h>
#include <math.h>

#define NR 8192
#define INF_ 512
#define OUTF 256
#define ALPHA 0.2f

typedef __attribute__((ext_vector_type(8))) short bf16x8;   // 8 bf16 = 4 VGPR
typedef __attribute__((ext_vector_type(4))) float f32x4;    // MFMA accumulator

#define MFMA(a, b, c) __builtin_amdgcn_mfma_f32_16x16x32_bf16((a), (b), (c), 0, 0, 0)

__device__ __forceinline__ ushort f2bf(float x) {  // RNE fp32->bf16
    unsigned u = __float_as_uint(x);
    return (ushort)((u + 0x7fff + ((u >> 16) & 1)) >> 16);
}
__device__ __forceinline__ float bf2f(ushort b) { return __uint_as_float((unsigned)b << 16); }

// ---------------- Kernel 1: H = X @ W (split-bf16 MFMA, inline conversion) ----
// 64x64 tile, 4 waves, BK=32. fp32 X/W converted to bf16 hi/lo at staging time.
// A staging: ar=(tid&15)+(tid>>6)*16, kg=(tid>>4)&3 -> consecutive lanes write
// consecutive LDS 16B slots (conflict-free b128 writes) while global reads
// stay segment-coalesced (16 rows x 128B contiguous per wave instr).
// LDS [kg4][idx64][8bf16], kg stride 512 ushorts; fragment reads are
// quarter-wave-contiguous 256B ds_read_b128 (conflict-free).
__global__ __launch_bounds__(256) void k_gemm(const float* __restrict__ X,
                                              const float* __restrict__ W,
                                              float* __restrict__ H) {
    __shared__ ushort sAhi[2048], sAlo[2048], sBhi[2048], sBlo[2048];
    const int tid = threadIdx.x;
    const int brow = blockIdx.x * 64, bcol = blockIdx.y * 64;
    const int lane = tid & 63, wr = tid >> 6;
    // A staging (conflict-free writes + coalesced reads)
    const int ar = (tid & 15) + (tid >> 6) * 16;   // row within tile
    const int akg = (tid >> 4) & 3;                // k-group within K-tile
    const float* gA = X + (size_t)(brow + ar) * INF_ + akg * 8;
    const int awslot = akg * 512 + ar * 8;         // [kg][idx=ar][8]
    // B staging: col s_i, k-rows s_kg*8+j (each j-load coalesced 256B)
    const int s_kg = tid >> 6, s_i = tid & 63;
    const float* gB = W + (size_t)(s_kg * 8) * OUTF + bcol + s_i;
    const int bwslot = tid * 8;                    // [kg=s_kg][idx=s_i][8]

    const int fr = lane & 15, kg = lane >> 4;
    const int aoff = kg * 512 + (wr * 16 + fr) * 8;
    const int boff = kg * 512 + fr * 8;            // + nf*128 per 16-col group

    f32x4 acc0 = {0.f,0.f,0.f,0.f}, acc1 = {0.f,0.f,0.f,0.f};
    f32x4 acc2 = {0.f,0.f,0.f,0.f}, acc3 = {0.f,0.f,0.f,0.f};

    float ra[8], rb[8];
    {
        float4 v0 = *(const float4*)gA, v1 = *(const float4*)(gA + 4);
        ra[0]=v0.x; ra[1]=v0.y; ra[2]=v0.z; ra[3]=v0.w;
        ra[4]=v1.x; ra[5]=v1.y; ra[6]=v1.z; ra[7]=v1.w;
#pragma unroll
        for (int j = 0; j < 8; ++j) rb[j] = gB[j * OUTF];
    }
    for (int t = 0; t < INF_ / 32; ++t) {
        ushort ah[8], al[8], bh[8], bl[8];
#pragma unroll
        for (int j = 0; j < 8; ++j) {
            ah[j] = f2bf(ra[j]); al[j] = f2bf(ra[j] - bf2f(ah[j]));
            bh[j] = f2bf(rb[j]); bl[j] = f2bf(rb[j] - bf2f(bh[j]));
        }
        *(uint4*)&sAhi[awslot] = *(uint4*)ah; *(uint4*)&sAlo[awslot] = *(uint4*)al;
        *(uint4*)&sBhi[bwslot] = *(uint4*)bh; *(uint4*)&sBlo[bwslot] = *(uint4*)bl;
        __syncthreads();
        if (t < INF_ / 32 - 1) {
            const float* pA = gA + (t + 1) * 32;
            const float* pB = gB + (size_t)(t + 1) * 32 * OUTF;
            float4 v0 = *(const float4*)pA, v1 = *(const float4*)(pA + 4);
            ra[0]=v0.x; ra[1]=v0.y; ra[2]=v0.z; ra[3]=v0.w;
            ra[4]=v1.x; ra[5]=v1.y; ra[6]=v1.z; ra[7]=v1.w;
#pragma unroll
            for (int j = 0; j < 8; ++j) rb[j] = pB[j * OUTF];
        }
        bf16x8 ahi = *(const bf16x8*)&sAhi[aoff];
        bf16x8 alo = *(const bf16x8*)&sAlo[aoff];
        bf16x8 bh0 = *(const bf16x8*)&sBhi[boff];
        bf16x8 bl0 = *(const bf16x8*)&sBlo[boff];
        bf16x8 bh1 = *(const bf16x8*)&sBhi[boff + 128];
        bf16x8 bl1 = *(const bf16x8*)&sBlo[boff + 128];
        bf16x8 bh2 = *(const bf16x8*)&sBhi[boff + 256];
        bf16x8 bl2 = *(const bf16x8*)&sBlo[boff + 256];
        bf16x8 bh3 = *(const bf16x8*)&sBhi[boff + 384];
        bf16x8 bl3 = *(const bf16x8*)&sBlo[boff + 384];
        acc0 = MFMA(ahi, bh0, acc0); acc0 = MFMA(ahi, bl0, acc0); acc0 = MFMA(alo, bh0, acc0);
        acc1 = MFMA(ahi, bh1, acc1); acc1 = MFMA(ahi, bl1, acc1); acc1 = MFMA(alo, bh1, acc1);
        acc2 = MFMA(ahi, bh2, acc2); acc2 = MFMA(ahi, bl2, acc2); acc2 = MFMA(alo, bh2, acc2);
        acc3 = MFMA(ahi, bh3, acc3); acc3 = MFMA(ahi, bl3, acc3); acc3 = MFMA(alo, bh3, acc3);
        __syncthreads();
    }
    const int orow = brow + wr * 16 + kg * 4;   // C/D: col=lane&15, row=(lane>>4)*4+q
    const int ocol = bcol + fr;
#pragma unroll
    for (int q = 0; q < 4; ++q) {
        H[(size_t)(orow + q) * OUTF + ocol + 0]  = acc0[q];
        H[(size_t)(orow + q) * OUTF + ocol + 16] = acc1[q];
        H[(size_t)(orow + q) * OUTF + ocol + 32] = acc2[q];
        H[(size_t)(orow + q) * OUTF + ocol + 48] = acc3[q];
    }
}

// ---------------- Kernel 2: src = H @ a[:F], dst = H @ a[F:] ----------------
__global__ __launch_bounds__(256) void k_srcdst(const float* __restrict__ H,
                                                const float* __restrict__ a,
                                                float* __restrict__ src,
                                                float* __restrict__ dst) {
    const int wv = threadIdx.x >> 6;
    const int ln = threadIdx.x & 63;
    const int row = blockIdx.x * 4 + wv;
    float4 hv = *(const float4*)(H + (size_t)row * OUTF + ln * 4);
    float4 a1 = *(const float4*)(a + ln * 4);
    float4 a2 = *(const float4*)(a + OUTF + ln * 4);
    float s = hv.x * a1.x + hv.y * a1.y + hv.z * a1.z + hv.w * a1.w;
    float d = hv.x * a2.x + hv.y * a2.y + hv.z * a2.z + hv.w * a2.w;
#pragma unroll
    for (int o = 32; o > 0; o >>= 1) {
        s += __shfl_down(s, o);
        d += __shfl_down(d, o);
    }
    if (ln == 0) { src[row] = s; dst[row] = d; }
}

// ---------------- Kernel 3: rank-by-counting "sort" ----------------
__global__ __launch_bounds__(256) void k_rank(const float* __restrict__ dstv,
                                              float* __restrict__ dsts,
                                              int* __restrict__ perm) {
    __shared__ float key[NR];
    const int tid = threadIdx.x;
#pragma unroll
    for (int i = 0; i < 8; ++i)
        *(float4*)(key + 4 * (tid + 256 * i)) = *(const float4*)(dstv + 4 * (tid + 256 * i));
    __syncthreads();
    const int el = blockIdx.x * 32 + (tid >> 3);
    const int sub = tid & 7;
    const float my = key[el];
    const int sbase = sub << 10;
    int cnt = 0;
#pragma unroll 4
    for (int i = 0; i < 256; ++i) {
        const int off = ((i + sub) << 2) & 1023;
        const int k0 = sbase + off;
        float4 v = *(const float4*)(key + k0);
        cnt += (int)((v.x < my) | ((v.x == my) & (k0 + 0 < el)));
        cnt += (int)((v.y < my) | ((v.y == my) & (k0 + 1 < el)));
        cnt += (int)((v.z < my) | ((v.z == my) & (k0 + 2 < el)));
        cnt += (int)((v.w < my) | ((v.w == my) & (k0 + 3 < el)));
    }
    cnt += __shfl_down(cnt, 4);
    cnt += __shfl_down(cnt, 2);
    cnt += __shfl_down(cnt, 1);
    if (sub == 0) {
        dsts[cnt] = my;
        perm[cnt] = el;
    }
}

// ---------------- Kernel 4: weights + scalar prefix scans (1 block) ----------------
__global__ __launch_bounds__(1024) void k_scan(const float* __restrict__ dsts,
                                               float* __restrict__ wplus,
                                               float* __restrict__ wminus,
                                               float* __restrict__ Splus,
                                               float* __restrict__ Sminus) {
    __shared__ float wsP[16], wsM[16];
    const int t = threadIdx.x;
    const int lane = t & 63;
    const float D = dsts[NR - 1];
    float4 v0 = *(const float4*)(dsts + t * 8);
    float4 v1 = *(const float4*)(dsts + t * 8 + 4);
    float vv[8] = {v0.x, v0.y, v0.z, v0.w, v1.x, v1.y, v1.z, v1.w};
    float wp[8], wm[8];
    float sp = 0.f, sm = 0.f;
#pragma unroll
    for (int j = 0; j < 8; ++j) {
        wp[j] = expf(vv[j] - D);
        wm[j] = expf(ALPHA * vv[j]);
        sp += wp[j]; sm += wm[j];
    }
    *(float4*)(wplus + t * 8)      = make_float4(wp[0], wp[1], wp[2], wp[3]);
    *(float4*)(wplus + t * 8 + 4)  = make_float4(wp[4], wp[5], wp[6], wp[7]);
    *(float4*)(wminus + t * 8)     = make_float4(wm[0], wm[1], wm[2], wm[3]);
    *(float4*)(wminus + t * 8 + 4) = make_float4(wm[4], wm[5], wm[6], wm[7]);
    float ip = sp, im = sm;
#pragma unroll
    for (int o = 1; o < 64; o <<= 1) {
        float tp = __shfl_up(ip, o);
        float tm = __shfl_up(im, o);
        if (lane >= o) { ip += tp; im += tm; }
    }
    if (lane == 63) { wsP[t >> 6] = ip; wsM[t >> 6] = im; }
    __syncthreads();
    if (t < 16) {
        float a = wsP[t], b = wsM[t];
#pragma unroll
        for (int o = 1; o < 16; o <<= 1) {
            float ta = __shfl_up(a, o);
            float tb = __shfl_up(b, o);
            if (t >= o) { a += ta; b += tb; }
        }
        wsP[t] = a; wsM[t] = b;
    }
    __syncthreads();
    const int w = t >> 6;
    float rp = (w ? wsP[w - 1] : 0.f) + (ip - sp);
    float rm = (w ? wsM[w - 1] : 0.f) + (im - sm);
#pragma unroll
    for (int j = 0; j < 8; ++j) {
        rp += wp[j]; rm += wm[j];
        Splus[t * 8 + j + 1] = rp;
        Sminus[t * 8 + j + 1] = rm;
    }
    if (t == 0) { Splus[0] = 0.f; Sminus[0] = 0.f; }
}

// ---------------- Kernel 5: per-chunk (32-row) weighted sums ----------------
__global__ __launch_bounds__(128) void k_chunksum(const float* __restrict__ H,
                                                  const int* __restrict__ perm,
                                                  const float* __restrict__ wplus,
                                                  const float* __restrict__ wminus,
                                                  float* __restrict__ chunkP,
                                                  float* __restrict__ chunkM) {
    __shared__ int sp[32];
    __shared__ float swp[32], swm[32];
    const int b = blockIdx.x >> 1;
    const int f = (blockIdx.x & 1) * 128 + threadIdx.x;
    if (threadIdx.x < 32) {
        int g = b * 32 + threadIdx.x;
        sp[threadIdx.x] = perm[g];
        swp[threadIdx.x] = wplus[g];
        swm[threadIdx.x] = wminus[g];
    }
    __syncthreads();
    float aP = 0.f, aM = 0.f;
    for (int k0 = 0; k0 < 32; k0 += 8) {
        float hv[8];
#pragma unroll
        for (int j = 0; j < 8; ++j) hv[j] = H[(size_t)sp[k0 + j] * OUTF + f];
#pragma unroll
        for (int j = 0; j < 8; ++j) {
            aP = fmaf(swp[k0 + j], hv[j], aP);
            aM = fmaf(swm[k0 + j], hv[j], aM);
        }
    }
    chunkP[b * OUTF + f] = aP;
    chunkM[b * OUTF + f] = aM;
}

// ---------------- Kernel 6: scan chunk sums per column ----------------
__global__ __launch_bounds__(64) void k_chunkscan(const float* __restrict__ chunkP,
                                                  const float* __restrict__ chunkM,
                                                  float* __restrict__ offP,
                                                  float* __restrict__ offM,
                                                  float* __restrict__ PrefP,
                                                  float* __restrict__ PrefM) {
    const int f = blockIdx.x;
    const bool minus = (blockIdx.y != 0);
    const float* sv = minus ? chunkM : chunkP;
    float* dv = minus ? offM : offP;
    float* tot = minus ? PrefM : PrefP;
    const int l = threadIdx.x;
    float v0 = sv[(4 * l + 0) * OUTF + f];
    float v1 = sv[(4 * l + 1) * OUTF + f];
    float v2 = sv[(4 * l + 2) * OUTF + f];
    float v3 = sv[(4 * l + 3) * OUTF + f];
    float s = v0 + v1 + v2 + v3;
    float incl = s;
#pragma unroll
    for (int o = 1; o < 64; o <<= 1) {
        float t = __shfl_up(incl, o);
        if (l >= o) incl += t;
    }
    float excl = incl - s;
    dv[(4 * l + 0) * OUTF + f] = excl;
    dv[(4 * l + 1) * OUTF + f] = excl + v0;
    dv[(4 * l + 2) * OUTF + f] = excl + v0 + v1;
    dv[(4 * l + 3) * OUTF + f] = excl + v0 + v1 + v2;
    if (l == 63) tot[(size_t)NR * OUTF + f] = incl;  // grand total row [8192]
}

// ---------------- Kernel 7: write full [8193][256] prefix arrays ----------------
__global__ __launch_bounds__(128) void k_writepref(const float* __restrict__ H,
                                                   const int* __restrict__ perm,
                                                   const float* __restrict__ wplus,
                                                   const float* __restrict__ wminus,
                                                   const float* __restrict__ offP,
                                                   const float* __restrict__ offM,
                                                   float* __restrict__ PrefP,
                                                   float* __restrict__ PrefM) {
    __shared__ int sp[32];
    __shared__ float swp[32], swm[32];
    const int b = blockIdx.x >> 1;
    const int f = (blockIdx.x & 1) * 128 + threadIdx.x;
    if (threadIdx.x < 32) {
        int g = b * 32 + threadIdx.x;
        sp[threadIdx.x] = perm[g];
        swp[threadIdx.x] = wplus[g];
        swm[threadIdx.x] = wminus[g];
    }
    __syncthreads();
    float aP = offP[b * OUTF + f];
    float aM = offM[b * OUTF + f];
    for (int k0 = 0; k0 < 32; k0 += 8) {
        float hv[8];
#pragma unroll
        for (int j = 0; j < 8; ++j) hv[j] = H[(size_t)sp[k0 + j] * OUTF + f];
#pragma unroll
        for (int j = 0; j < 8; ++j) {
            int g = b * 32 + k0 + j;
            PrefP[(size_t)g * OUTF + f] = aP;
            PrefM[(size_t)g * OUTF + f] = aM;
            aP = fmaf(swp[k0 + j], hv[j], aP);
            aM = fmaf(swm[k0 + j], hv[j], aM);
        }
    }
}

// ---------------- Kernel 8: per-row combine + ELU ----------------
__global__ __launch_bounds__(256) void k_out(const float* __restrict__ src,
                                             const float* __restrict__ dsts,
                                             const float* __restrict__ Splus,
                                             const float* __restrict__ Sminus,
                                             const float* __restrict__ PrefP,
                                             const float* __restrict__ PrefM,
                                             float* __restrict__ out) {
    const int i = blockIdx.x, f = threadIdx.x;
    const float si = src[i];
    const float D = dsts[NR - 1];
    const float thr = -si;
    int lo = 0, hi = NR;
    while (lo < hi) {
        int mid = (lo + hi) >> 1;
        if (dsts[mid] <= thr) lo = mid + 1; else hi = mid;
    }
    const int t = lo;
    const float cP = expf(si + D);
    const float cM = expf(ALPHA * si);
    const float SP = Splus[NR] - Splus[t];
    const float SM = Sminus[t];
    const float inv = 1.f / (cP * SP + cM * SM);
    const float pP = PrefP[(size_t)NR * OUTF + f] - PrefP[(size_t)t * OUTF + f];
    const float pM = PrefM[(size_t)t * OUTF + f];
    const float v = (cP * pP + cM * pM) * inv;
    out[(size_t)i * OUTF + f] = v > 0.f ? v : expm1f(v);
}

extern "C" void kernel_launch(void* const* d_in, const int* in_sizes, int n_in,
                              void* d_out, int out_size, void* d_ws, size_t ws_size,
                              hipStream_t stream) {
    const float* X = (const float*)d_in[0];
    // d_in[1] = adj (unused by reference forward)
    const float* W = (const float*)d_in[2];
    const float* a = (const float*)d_in[3];
    float* out = (float*)d_out;

    char* ws = (char*)d_ws;
    size_t off = 0;
    auto carve = [&](size_t bytes) -> void* {
        void* p = ws + off;
        off += (bytes + 1023) & ~(size_t)1023;
        return p;
    };
    float* H      = (float*)carve((size_t)NR * OUTF * 4);
    float* src    = (float*)carve(NR * 4);
    float* dstv   = (float*)carve(NR * 4);
    float* dsts   = (float*)carve(NR * 4);
    int*   perm   = (int*)carve(NR * 4);
    float* wplus  = (float*)carve(NR * 4);
    float* wminus = (float*)carve(NR * 4);
    float* Splus  = (float*)carve((NR + 1) * 4);
    float* Sminus = (float*)carve((NR + 1) * 4);
    float* chunkP = (float*)carve(256 * OUTF * 4);
    float* chunkM = (float*)carve(256 * OUTF * 4);
    float* offP   = (float*)carve(256 * OUTF * 4);
    float* offM   = (float*)carve(256 * OUTF * 4);
    float* PrefP  = (float*)carve((size_t)(NR + 1) * OUTF * 4);
    float* PrefM  = (float*)carve((size_t)(NR + 1) * OUTF * 4);

    k_gemm<<<dim3(NR / 64, OUTF / 64), 256, 0, stream>>>(X, W, H);
    k_srcdst<<<NR / 4, 256, 0, stream>>>(H, a, src, dstv);
    k_rank<<<NR / 32, 256, 0, stream>>>(dstv, dsts, perm);
    k_scan<<<1, 1024, 0, stream>>>(dsts, wplus, wminus, Splus, Sminus);
    k_chunksum<<<512, 128, 0, stream>>>(H, perm, wplus, wminus, chunkP, chunkM);
    k_chunkscan<<<dim3(OUTF, 2), 64, 0, stream>>>(chunkP, chunkM, offP, offM, PrefP, PrefM);
    k_writepref<<<512, 128, 0, stream>>>(H, perm, wplus, wminus, offP, offM, PrefP, PrefM);
    k_out<<<NR, 256, 0, stream>>>(src, dsts, Splus, Sminus, PrefP, PrefM, out);
}